// Round 18
// baseline (283.250 us; speedup 1.0000x reference)
//
#include <hip/hip_runtime.h>

#define B_  4
#define LQ  1024
#define LC  2047
#define LK  2048
#define F_  2048
#define H_  16
#define DH  128
#define NT  (LK / 64)

typedef __attribute__((ext_vector_type(4))) float f32x4;
typedef __attribute__((ext_vector_type(8))) __bf16 bf16x8;
typedef __attribute__((ext_vector_type(8))) unsigned short u16x8;

#define GLD16(gp, lp)                                                          \
  __builtin_amdgcn_global_load_lds(                                            \
      (const __attribute__((address_space(1))) void*)(gp),                     \
      (__attribute__((address_space(3))) void*)(lp), 16, 0, 0)

__device__ __forceinline__ unsigned short f2bf(float f) {
  unsigned u = __float_as_uint(f);
  u += 0x7FFFu + ((u >> 16) & 1u);
  return (unsigned short)(u >> 16);
}
__device__ __forceinline__ float bf2f(unsigned short u) {
  return __uint_as_float((unsigned)u << 16);
}
// pack two f32 -> two truncated bf16 in one u32 (lo = a, hi = b)
__device__ __forceinline__ unsigned pack_bf2(float a, float b) {
  return (__float_as_uint(b) & 0xffff0000u) | (__float_as_uint(a) >> 16);
}
// pack with RNE rounding
__device__ __forceinline__ unsigned pack_bf2_rne(float a, float b) {
  return (unsigned)f2bf(a) | ((unsigned)f2bf(b) << 16);
}

// ---------------- cos/sin table: [pos 0..2047][j 0..63] ----------------
__global__ void k_tables(float* __restrict__ cost, float* __restrict__ sint) {
  int idx = blockIdx.x * 256 + threadIdx.x;   // 2048*64 entries
  int pos = idx >> 6, j = idx & 63;
  float theta = powf(1000.0f, -(float)j / 64.0f);
  float a = (float)pos * theta;
  cost[idx] = cosf(a);
  sint[idx] = sinf(a);
}

// ------- key_new/val_new partials: grid (8 colblk, 2 kv, 8 kchunk) ------
__global__ void k_gemv_part(const float* __restrict__ kv, const float* __restrict__ Wk,
                            const float* __restrict__ Wv, float* __restrict__ part) {
  __shared__ float kvs[4][256];
  int tid = threadIdx.x, z = blockIdx.z;
#pragma unroll
  for (int b = 0; b < 4; ++b) kvs[b][tid] = kv[b * F_ + z * 256 + tid];
  __syncthreads();
  const float* W = blockIdx.y ? Wv : Wk;
  int col = blockIdx.x * 256 + tid;
  float a0 = 0.f, a1 = 0.f, a2 = 0.f, a3 = 0.f;
  for (int k = 0; k < 256; ++k) {
    float w = W[(size_t)(z * 256 + k) * F_ + col];
    a0 = fmaf(kvs[0][k], w, a0);
    a1 = fmaf(kvs[1][k], w, a1);
    a2 = fmaf(kvs[2][k], w, a2);
    a3 = fmaf(kvs[3][k], w, a3);
  }
  float* o = part + (size_t)(blockIdx.y * 8 + z) * 8192;
  o[col] = a0; o[2048 + col] = a1; o[4096 + col] = a2; o[6144 + col] = a3;
}

// ------- fused: cache copy-out + append (inline 8-way partial reduce),
//         build RoPE'd K (bf16) + V (bf16). float4 path: j-pair per thread.
__global__ void k_prep_kv(const float* __restrict__ cache, const float* __restrict__ gpart,
                          const float* __restrict__ cost, const float* __restrict__ sint,
                          float* __restrict__ cache_out,
                          unsigned short* __restrict__ Kr, unsigned short* __restrict__ Vb) {
  int t = blockIdx.x * 256 + threadIdx.x;   // 4*2048*16*32 = 2^22 threads
  int j2 = t & 31, h = (t >> 5) & 15, pos = (t >> 9) & 2047, b = t >> 20;
  int f = h * DH + j2 * 2;                  // even
  float4 x, y;                              // {k(f),v(f),k(f+1),v(f+1)}, same at f+64
  if (pos < LC) {
    const float* p = cache + ((size_t)(b * LC + pos) * F_ + f) * 2;
    x = *(const float4*)p;
    y = *(const float4*)(p + 128);          // f + 64
  } else {
    float k0 = 0, v0 = 0, k1 = 0, v1 = 0, k2 = 0, v2 = 0, k3 = 0, v3 = 0;
#pragma unroll
    for (int z = 0; z < 8; ++z) {
      const float* gk = gpart + (size_t)z * 8192 + b * 2048;
      const float* gv = gpart + (size_t)(8 + z) * 8192 + b * 2048;
      k0 += gk[f];      k1 += gk[f + 1];
      k2 += gk[f + 64]; k3 += gk[f + 65];
      v0 += gv[f];      v1 += gv[f + 1];
      v2 += gv[f + 64]; v3 += gv[f + 65];
    }
    x = make_float4(k0, v0, k1, v1);
    y = make_float4(k2, v2, k3, v3);
  }
  float* o = cache_out + ((size_t)(b * LK + pos) * F_ + f) * 2;
  *(float4*)o = x;
  *(float4*)(o + 128) = y;
  int j = j2 * 2;
  float c0 = cost[pos * 64 + j],     s0 = sint[pos * 64 + j];
  float c1 = cost[pos * 64 + j + 1], s1 = sint[pos * 64 + j + 1];
  size_t kb = ((size_t)(b * H_ + h) * LK + pos) * DH + j;
  *(unsigned*)&Kr[kb]      = pack_bf2_rne(x.x * c0 - y.x * s0, x.z * c1 - y.z * s1);
  *(unsigned*)&Kr[kb + 64] = pack_bf2_rne(y.x * c0 + x.x * s0, y.z * c1 + x.z * s1);
  *(unsigned*)&Vb[kb]      = pack_bf2_rne(x.y, x.w);
  *(unsigned*)&Vb[kb + 64] = pack_bf2_rne(y.y, y.w);
}

// ------- z<2: W [K][N] f32 -> Wt [N][K] bf16;  z>=2: q f32 -> bf16 ------
__global__ void k_transpose_w(const float* __restrict__ Wq, const float* __restrict__ Wo,
                              unsigned short* __restrict__ WqT, unsigned short* __restrict__ WoT,
                              const float* __restrict__ qf, unsigned short* __restrict__ qb) {
  __shared__ float tile[32][33];
  int z = blockIdx.z;
  if (z >= 2) {
    int t = ((z - 2) * 4096 + blockIdx.y * 64 + blockIdx.x) * 256 + threadIdx.x;
    float4 v = ((const float4*)qf)[t];
    ushort4 o;
    o.x = f2bf(v.x); o.y = f2bf(v.y); o.z = f2bf(v.z); o.w = f2bf(v.w);
    ((ushort4*)qb)[t] = o;
    return;
  }
  const float* W = z ? Wo : Wq;
  unsigned short* Wt = z ? WoT : WqT;
  int n0 = blockIdx.x * 32, k0 = blockIdx.y * 32;
  int tx = threadIdx.x & 31, ty = threadIdx.x >> 5;
#pragma unroll
  for (int p = 0; p < 4; ++p)
    tile[ty + p * 8][tx] = W[(size_t)(k0 + ty + p * 8) * F_ + n0 + tx];
  __syncthreads();
#pragma unroll
  for (int p = 0; p < 4; ++p)
    Wt[(size_t)(n0 + ty + p * 8) * F_ + k0 + tx] = f2bf(tile[tx][ty + p * 8]);
}

// ---- bf16 MFMA GEMM: BM=256, BN=128, BK=64, 8 waves, dbuf LDS ----------
// 2 barriers per K-tile (R14's 6-barrier phasing was stall-bound at our
// BN=128 cluster size): {bar; issue 6 GLD16(t+1); vmcnt(6); bar; read all
// 16 frags; lgkmcnt(0); 32-MFMA setprio cluster}. Counted vmcnt, never 0.
// MODE 0: plain f32 C.  MODE 2: fused RoPE epilogue (BN == head dim).
template <int MODE>
__launch_bounds__(512)
__global__ void k_gemm(const unsigned short* __restrict__ A, const unsigned short* __restrict__ Bt,
                       void* __restrict__ Cv, const float* __restrict__ cost,
                       const float* __restrict__ sint, int M, int N, int K) {
  __shared__ __align__(16) unsigned short SM[49152];  // A:2x16384, B:2x8192 (ushorts)
  int tid = threadIdx.x, wid = tid >> 6, l = tid & 63;
  int wm = wid >> 1, wn = wid & 1;
  int lr = l & 15, lg = l >> 4;
  int m0 = blockIdx.y * 256, n0 = blockIdx.x * 128;

  int agoff[4], aloff[4], bgoff[2], bloff[2];
#pragma unroll
  for (int p = 0; p < 4; ++p) {
    int g = (p >> 1) * 1024 + (p & 1) * 512 + tid;
    int row = g >> 3, c = g & 7;
    agoff[p] = row * K + (c ^ (row & 7)) * 8;
    aloff[p] = g * 8;
  }
#pragma unroll
  for (int p = 0; p < 2; ++p) {
    int g = p * 512 + tid;
    int row = g >> 3, c = g & 7;
    bgoff[p] = row * K + (c ^ (row & 7)) * 8;
    bloff[p] = g * 8;
  }
  const unsigned short* Ag = A + (size_t)m0 * K;
  const unsigned short* Bg = Bt + (size_t)n0 * K;

  int fsw = (lr & 7);
  f32x4 acc[4][4];
#pragma unroll
  for (int i = 0; i < 4; ++i)
#pragma unroll
    for (int j = 0; j < 4; ++j) acc[i][j] = (f32x4){0.f, 0.f, 0.f, 0.f};

  int nk = K >> 6;
  // prologue: stage tile 0 into buf0
#pragma unroll
  for (int p = 0; p < 4; ++p) GLD16(Ag + agoff[p], SM + aloff[p]);
#pragma unroll
  for (int p = 0; p < 2; ++p) GLD16(Bg + bgoff[p], SM + 32768 + bloff[p]);

  for (int kt = 0; kt < nk; ++kt) {
    int cur = kt & 1;
    unsigned short* Ac = SM + cur * 16384;
    unsigned short* Bc = SM + 32768 + cur * 8192;
    unsigned short* An = SM + (cur ^ 1) * 16384;
    unsigned short* Bn = SM + 32768 + (cur ^ 1) * 8192;
    int knext = ((kt + 1 < nk) ? (kt + 1) : 0) << 6;

    __builtin_amdgcn_s_barrier();          // all waves done reading buf^1
    __builtin_amdgcn_sched_barrier(0);
    // issue all 6 loads of tile t+1 into buf^1
    GLD16(Ag + knext + agoff[0], An + aloff[0]);
    GLD16(Ag + knext + agoff[1], An + aloff[1]);
    GLD16(Ag + knext + agoff[2], An + aloff[2]);
    GLD16(Ag + knext + agoff[3], An + aloff[3]);
    GLD16(Bg + knext + bgoff[0], Bn + bloff[0]);
    GLD16(Bg + knext + bgoff[1], Bn + bloff[1]);
    // tile t's 6 loads (issued one iter ago) complete; t+1's stay in flight
    asm volatile("s_waitcnt vmcnt(6)" ::: "memory");
    __builtin_amdgcn_sched_barrier(0);
    __builtin_amdgcn_s_barrier();          // tile t visible to all waves
    __builtin_amdgcn_sched_barrier(0);

    // read ALL fragments for this K-tile
    bf16x8 af[2][4], bfr[2][4];
#pragma unroll
    for (int kw = 0; kw < 2; ++kw)
#pragma unroll
      for (int mi = 0; mi < 4; ++mi)
        af[kw][mi] = *(const bf16x8*)&Ac[(wm * 64 + mi * 16 + lr) * 64 + (((kw * 4 + lg) ^ fsw) << 3)];
#pragma unroll
    for (int kw = 0; kw < 2; ++kw)
#pragma unroll
      for (int ni = 0; ni < 4; ++ni)
        bfr[kw][ni] = *(const bf16x8*)&Bc[(wn * 64 + ni * 16 + lr) * 64 + (((kw * 4 + lg) ^ fsw) << 3)];
    asm volatile("s_waitcnt lgkmcnt(0)" ::: "memory");
    __builtin_amdgcn_sched_barrier(0);
    __builtin_amdgcn_s_setprio(1);
#pragma unroll
    for (int ni = 0; ni < 4; ++ni)
#pragma unroll
      for (int kw = 0; kw < 2; ++kw)
#pragma unroll
        for (int mi = 0; mi < 4; ++mi)
          acc[mi][ni] = __builtin_amdgcn_mfma_f32_16x16x32_bf16(af[kw][mi], bfr[kw][ni], acc[mi][ni], 0, 0, 0);
    __builtin_amdgcn_s_setprio(0);
  }
  // drain the dummy prefetch before LDS reuse / exit
  asm volatile("s_waitcnt vmcnt(0)" ::: "memory");
  __syncthreads();

  if (MODE == 0) {
#pragma unroll
    for (int mi = 0; mi < 4; ++mi)
#pragma unroll
      for (int ni = 0; ni < 4; ++ni) {
        int row = m0 + wm * 64 + mi * 16 + lg * 4;
        int col = n0 + wn * 64 + ni * 16 + lr;
#pragma unroll
        for (int r = 0; r < 4; ++r)
          ((float*)Cv)[(size_t)(row + r) * N + col] = acc[mi][ni][r];
      }
  } else {
    unsigned short* X = SM;                 // [256][130] bf16 exchange tile
#pragma unroll
    for (int mi = 0; mi < 4; ++mi)
#pragma unroll
      for (int ni = 0; ni < 4; ++ni) {
        int lrow = wm * 64 + mi * 16 + lg * 4;
        int col = wn * 64 + ni * 16 + lr;
#pragma unroll
        for (int r = 0; r < 4; ++r)
          X[(lrow + r) * 130 + col] = f2bf(acc[mi][ni][r]);
      }
    __syncthreads();
    int h = blockIdx.x;
    const float scale = 0.12751743343788055f;  // (1/sqrt(128)) * log2(e)
    unsigned short* Q = (unsigned short*)Cv;
#pragma unroll
    for (int mi = 0; mi < 4; ++mi) {
      int lrow0 = wm * 64 + mi * 16 + lg * 4;
#pragma unroll
      for (int r = 0; r < 4; ++r) {
        int lrow = lrow0 + r;
        int grow = m0 + lrow;
        int qi = grow & 1023, b = grow >> 10;
        size_t obase = ((size_t)(b * H_ + h) * LQ + qi) * DH;
#pragma unroll
        for (int ni = 0; ni < 4; ++ni) {
          int col = wn * 64 + ni * 16 + lr;
          int jj = col & 63;
          float c = cost[qi * 64 + jj], s = sint[qi * 64 + jj];
          float a = acc[mi][ni][r];
          float a2 = bf2f(X[lrow * 130 + (col ^ 64)]);
          float o = (col < 64) ? (a * c - a2 * s) : (a * c + a2 * s);
          Q[obase + col] = f2bf(o * scale);
        }
      }
    }
  }
}

// --- flash attention: 4 waves x 32 q-rows, BK=64, single-buffer K -------
// (R16 kernel: 107.6 us, VGPR 116, no spill.)
__launch_bounds__(256, 2)
__global__ void k_attn(const unsigned short* __restrict__ Qr, const unsigned short* __restrict__ Kr,
                       const unsigned short* __restrict__ Vb, unsigned short* __restrict__ Oo) {
  __shared__ __align__(16) unsigned short Ks[64 * 128];     // 16 KB, chunk-swizzled
  __shared__ __align__(16) unsigned short Vt[128][72];      // 18 KB
  __shared__ __align__(16) unsigned short Pb[4][32][72];    // 18 KB
  int tid = threadIdx.x, wid = tid >> 6, l = tid & 63;
  int lr = l & 15, lg = l >> 4;
  int bh = blockIdx.x, q0 = blockIdx.y * 128 + wid * 32;    // grid (64,8)
  const unsigned short* Qb = Qr + ((size_t)bh * LQ + q0) * DH;
  const unsigned short* Kb = Kr + (size_t)bh * LK * DH;
  const unsigned short* Vp = Vb + (size_t)bh * LK * DH;

  bf16x8 qf[2][4];
#pragma unroll
  for (int s = 0; s < 2; ++s)
#pragma unroll
    for (int c = 0; c < 4; ++c)
      qf[s][c] = *(const bf16x8*)(Qb + (size_t)(s * 16 + lr) * DH + c * 32 + lg * 8);

  u16x8 one_u;
#pragma unroll
  for (int e = 0; e < 8; ++e) one_u[e] = 0x3F80;
  bf16x8 vone = *(const bf16x8*)&one_u;

  int gkoff[4], lkoff[4];
#pragma unroll
  for (int p = 0; p < 4; ++p) {
    int g = tid + p * 256, row = g >> 4, cc = g & 15;
    gkoff[p] = row * DH + (cc ^ (row & 15)) * 8;
    lkoff[p] = g * 8;
  }

  f32x4 oacc[2][8];
#pragma unroll
  for (int s = 0; s < 2; ++s)
#pragma unroll
    for (int i = 0; i < 8; ++i) oacc[s][i] = (f32x4){0.f, 0.f, 0.f, 0.f};
  f32x4 lacc[2] = {(f32x4){0.f, 0.f, 0.f, 0.f}, (f32x4){0.f, 0.f, 0.f, 0.f}};
  float mrun[2][4] = {{-1e30f, -1e30f, -1e30f, -1e30f}, {-1e30f, -1e30f, -1e30f, -1e30f}};

  int kp = tid >> 4, cg = tid & 15;

  // prologue: V(0) -> regs (keys kp, kp+16, kp+32, kp+48)
  const unsigned short* vs0 = Vp + (size_t)kp * DH + cg * 8;
  u16x8 v00 = *(const u16x8*)(vs0);
  u16x8 v01 = *(const u16x8*)(vs0 + 16 * DH);
  u16x8 v10 = *(const u16x8*)(vs0 + 32 * DH);
  u16x8 v11 = *(const u16x8*)(vs0 + 48 * DH);

  for (int kt = 0; kt < NT; ++kt) {
    __builtin_amdgcn_s_barrier();      // A: all waves done reading tile t-1
    __builtin_amdgcn_sched_barrier(0);
    // stage K(t) async into the single K buffer
    {
      const unsigned short* Kt = Kb + (size_t)kt * 64 * DH;
#pragma unroll
      for (int p = 0; p < 4; ++p) GLD16(Kt + gkoff[p], Ks + lkoff[p]);
    }
    // V(t) ds_writes from regs (packed u32, swizzled)
#pragma unroll
    for (int pp = 0; pp < 2; ++pp) {
      int j = kp + pp * 16;
      int kks = j ^ ((cg & 7) << 2);
      u16x8 a = pp ? v10 : v00, b2 = pp ? v11 : v01;
#pragma unroll
      for (int e = 0; e < 8; ++e) {
        unsigned pack = (unsigned)a[e] | ((unsigned)b2[e] << 16);
        *(unsigned*)&Vt[cg * 8 + e][kks * 2] = pack;
      }
    }
    // prefetch V(t+1) into regs (dummy re-read of t on last iter)
    {
      int tn = (kt + 1 < NT) ? kt + 1 : kt;
      const unsigned short* vn = Vp + (size_t)(tn * 64 + kp) * DH + cg * 8;
      v00 = *(const u16x8*)(vn);
      v01 = *(const u16x8*)(vn + 16 * DH);
      v10 = *(const u16x8*)(vn + 32 * DH);
      v11 = *(const u16x8*)(vn + 48 * DH);
    }
    // K(t)'s 4 GLD16 (oldest) done; V(t+1) still flying; Vt writes committed
    asm volatile("s_waitcnt vmcnt(4) lgkmcnt(0)" ::: "memory");
    __builtin_amdgcn_sched_barrier(0);
    __builtin_amdgcn_s_barrier();      // B: K(t) + Vt(t) visible to all
    __builtin_amdgcn_sched_barrier(0);

    // S = Q K^T : K fragment loaded once, used by both subtiles
    f32x4 sf[2][4];
    __builtin_amdgcn_s_setprio(1);
#pragma unroll
    for (int ct = 0; ct < 4; ++ct) {
      f32x4 s0 = (f32x4){0.f, 0.f, 0.f, 0.f};
      f32x4 s1 = (f32x4){0.f, 0.f, 0.f, 0.f};
#pragma unroll
      for (int ck = 0; ck < 4; ++ck) {
        bf16x8 kf = *(const bf16x8*)&Ks[(ct * 16 + lr) * 128 + (((ck * 4 + lg) ^ lr) << 3)];
        s0 = __builtin_amdgcn_mfma_f32_16x16x32_bf16(qf[0][ck], kf, s0, 0, 0, 0);
        s1 = __builtin_amdgcn_mfma_f32_16x16x32_bf16(qf[1][ck], kf, s1, 0, 0, 0);
      }
      sf[0][ct] = s0; sf[1][ct] = s1;
    }
    __builtin_amdgcn_s_setprio(0);

    // defer-max online softmax (both subtiles share the skip test)
    float pmax[2][4];
    bool allok = true;
#pragma unroll
    for (int s = 0; s < 2; ++s)
#pragma unroll
      for (int r = 0; r < 4; ++r) {
        pmax[s][r] = fmaxf(fmaxf(sf[s][0][r], sf[s][1][r]), fmaxf(sf[s][2][r], sf[s][3][r]));
        allok = allok && (pmax[s][r] - mrun[s][r] <= 8.0f);
      }
    if (!__all(allok)) {
#pragma unroll
      for (int s = 0; s < 2; ++s)
#pragma unroll
        for (int r = 0; r < 4; ++r) {
          float m = pmax[s][r];
#pragma unroll
          for (int off = 1; off < 16; off <<= 1) m = fmaxf(m, __shfl_xor(m, off));
          float mnew = fmaxf(mrun[s][r], m);
          float scl = exp2f(mrun[s][r] - mnew);
          lacc[s][r] *= scl;
#pragma unroll
          for (int dt = 0; dt < 8; ++dt) oacc[s][dt][r] *= scl;
          mrun[s][r] = mnew;
        }
    }
    // P stores: two packed u32 per (s,r) at permuted cols lr and 16+lr
#pragma unroll
    for (int s = 0; s < 2; ++s)
#pragma unroll
      for (int r = 0; r < 4; ++r) {
        float p0 = exp2f(sf[s][0][r] - mrun[s][r]);
        float p1 = exp2f(sf[s][1][r] - mrun[s][r]);
        float p2 = exp2f(sf[s][2][r] - mrun[s][r]);
        float p3 = exp2f(sf[s][3][r] - mrun[s][r]);
        unsigned* row = (unsigned*)&Pb[wid][s * 16 + lg * 4 + r][0];
        row[lr]      = pack_bf2(p0, p1);
        row[16 + lr] = pack_bf2(p2, p3);
      }

    // O += P V : V fragment loaded once, used by both subtiles
    bf16x8 pf00 = *(const bf16x8*)&Pb[wid][lr][lg * 8];
    bf16x8 pf01 = *(const bf16x8*)&Pb[wid][lr][32 + lg * 8];
    bf16x8 pf10 = *(const bf16x8*)&Pb[wid][16 + lr][lg * 8];
    bf16x8 pf11 = *(const bf16x8*)&Pb[wid][16 + lr][32 + lg * 8];
    __builtin_amdgcn_s_setprio(1);
    // l-rowsum via ones-MFMA (every lane ends with its row's full sum)
    lacc[0] = __builtin_amdgcn_mfma_f32_16x16x32_bf16(pf00, vone, lacc[0], 0, 0, 0);
    lacc[0] = __builtin_amdgcn_mfma_f32_16x16x32_bf16(pf01, vone, lacc[0], 0, 0, 0);
    lacc[1] = __builtin_amdgcn_mfma_f32_16x16x32_bf16(pf10, vone, lacc[1], 0, 0, 0);
    lacc[1] = __builtin_amdgcn_mfma_f32_16x16x32_bf16(pf11, vone, lacc[1], 0, 0, 0);
#pragma unroll
    for (int dt = 0; dt < 8; ++dt) {
      int d = dt * 16 + lr;
      int x = (d >> 3) & 7;
      bf16x8 v0 = *(const bf16x8*)&Vt[d][(lg ^ x) << 3];
      bf16x8 v1 = *(const bf16x8*)&Vt[d][((4 + lg) ^ x) << 3];
      oacc[0][dt] = __builtin_amdgcn_mfma_f32_16x16x32_bf16(pf00, v0, oacc[0][dt], 0, 0, 0);
      oacc[0][dt] = __builtin_amdgcn_mfma_f32_16x16x32_bf16(pf01, v1, oacc[0][dt], 0, 0, 0);
      oacc[1][dt] = __builtin_amdgcn_mfma_f32_16x16x32_bf16(pf10, v0, oacc[1][dt], 0, 0, 0);
      oacc[1][dt] = __builtin_amdgcn_mfma_f32_16x16x32_bf16(pf11, v1, oacc[1][dt], 0, 0, 0);
    }
    __builtin_amdgcn_s_setprio(0);
  }

  int b = bh >> 4, h = bh & 15;
#pragma unroll
  for (int s = 0; s < 2; ++s)
#pragma unroll
    for (int r = 0; r < 4; ++r) {
      float inv = 1.0f / lacc[s][r];
      int qrow = q0 + s * 16 + lg * 4 + r;
      size_t base = ((size_t)(b * LQ + qrow)) * F_ + h * DH;
#pragma unroll
      for (int dt = 0; dt < 8; ++dt)
        Oo[base + dt * 16 + lr] = f2bf(oacc[s][dt][r] * inv);
    }
}

extern "C" void kernel_launch(void* const* d_in, const int* in_sizes, int n_in,
                              void* d_out, int out_size, void* d_ws, size_t ws_size,
                              hipStream_t stream) {
  const float* kv    = (const float*)d_in[0];
  const float* q     = (const float*)d_in[1];
  const float* cache = (const float*)d_in[2];
  const float* Wq    = (const float*)d_in[3];
  const float* Wk    = (const float*)d_in[4];
  const float* Wv    = (const float*)d_in[5];
  const float* Wo    = (const float*)d_in[6];

  float* logits    = (float*)d_out;
  float* cache_out = logits + (size_t)B_ * LQ * F_;

  char* ws = (char*)d_ws;
  float* cost          = (float*)(ws);                       // 512 KB
  float* sint          = (float*)(ws + 524288);              // 512 KB
  float* gpart         = (float*)(ws + 1114112);             // 512 KB
  unsigned short* WqT  = (unsigned short*)(ws + 1638400);    // 8 MB
  unsigned short* WoT  = (unsigned short*)(ws + 10027008);   // 8 MB
  unsigned short* qbf  = (unsigned short*)(ws + 18415616);   // 16 MB
  unsigned short* Qro  = (unsigned short*)(ws + 35192832);   // 16 MB
  unsigned short* Kro  = (unsigned short*)(ws + 51970048);   // 32 MB
  unsigned short* Vbf  = (unsigned short*)(ws + 85524480);   // 32 MB
  unsigned short* attno = (unsigned short*)(ws + 127467520); // 16 MB

  k_tables<<<dim3(512), dim3(256), 0, stream>>>(cost, sint);
  k_gemv_part<<<dim3(8, 2, 8), dim3(256), 0, stream>>>(kv, Wk, Wv, gpart);
  k_prep_kv<<<dim3(16384), dim3(256), 0, stream>>>(cache, gpart, cost, sint,
                                                   cache_out, Kro, Vbf);
  k_transpose_w<<<dim3(64, 64, 4), dim3(256), 0, stream>>>(Wq, Wo, WqT, WoT, q, qbf);
  k_gemm<2><<<dim3(16, 16), dim3(512), 0, stream>>>(qbf, WqT, Qro, cost, sint,
                                                    B_ * LQ, F_, F_);
  k_attn<<<dim3(64, 8), dim3(256), 0, stream>>>(Qro, Kro, Vbf, attno);
  k_gemm<0><<<dim3(16, 16), dim3(512), 0, stream>>>(attno, WoT, logits, nullptr, nullptr,
                                                    B_ * LQ, F_, F_);
}

// Round 19
// 274.825 us; speedup vs baseline: 1.0307x; 1.0307x over previous
//
#include <hip/hip_runtime.h>

#define B_  4
#define LQ  1024
#define LC  2047
#define LK  2048
#define F_  2048
#define H_  16
#define DH  128
#define NT  (LK / 64)

typedef __attribute__((ext_vector_type(4))) float f32x4;
typedef __attribute__((ext_vector_type(8))) __bf16 bf16x8;
typedef __attribute__((ext_vector_type(8))) unsigned short u16x8;

#define GLD16(gp, lp)                                                          \
  __builtin_amdgcn_global_load_lds(                                            \
      (const __attribute__((address_space(1))) void*)(gp),                     \
      (__attribute__((address_space(3))) void*)(lp), 16, 0, 0)

__device__ __forceinline__ unsigned short f2bf(float f) {
  unsigned u = __float_as_uint(f);
  u += 0x7FFFu + ((u >> 16) & 1u);
  return (unsigned short)(u >> 16);
}
__device__ __forceinline__ float bf2f(unsigned short u) {
  return __uint_as_float((unsigned)u << 16);
}
// pack two f32 -> two truncated bf16 in one u32 (lo = a, hi = b)
__device__ __forceinline__ unsigned pack_bf2(float a, float b) {
  return (__float_as_uint(b) & 0xffff0000u) | (__float_as_uint(a) >> 16);
}
// pack with RNE rounding
__device__ __forceinline__ unsigned pack_bf2_rne(float a, float b) {
  return (unsigned)f2bf(a) | ((unsigned)f2bf(b) << 16);
}

// ---------------- cos/sin table: [pos 0..2047][j 0..63] ----------------
__global__ void k_tables(float* __restrict__ cost, float* __restrict__ sint) {
  int idx = blockIdx.x * 256 + threadIdx.x;   // 2048*64 entries
  int pos = idx >> 6, j = idx & 63;
  float theta = powf(1000.0f, -(float)j / 64.0f);
  float a = (float)pos * theta;
  cost[idx] = cosf(a);
  sint[idx] = sinf(a);
}

// ------- key_new/val_new partials: grid (8 colblk, 2 kv, 8 kchunk) ------
__global__ void k_gemv_part(const float* __restrict__ kv, const float* __restrict__ Wk,
                            const float* __restrict__ Wv, float* __restrict__ part) {
  __shared__ float kvs[4][256];
  int tid = threadIdx.x, z = blockIdx.z;
#pragma unroll
  for (int b = 0; b < 4; ++b) kvs[b][tid] = kv[b * F_ + z * 256 + tid];
  __syncthreads();
  const float* W = blockIdx.y ? Wv : Wk;
  int col = blockIdx.x * 256 + tid;
  float a0 = 0.f, a1 = 0.f, a2 = 0.f, a3 = 0.f;
  for (int k = 0; k < 256; ++k) {
    float w = W[(size_t)(z * 256 + k) * F_ + col];
    a0 = fmaf(kvs[0][k], w, a0);
    a1 = fmaf(kvs[1][k], w, a1);
    a2 = fmaf(kvs[2][k], w, a2);
    a3 = fmaf(kvs[3][k], w, a3);
  }
  float* o = part + (size_t)(blockIdx.y * 8 + z) * 8192;
  o[col] = a0; o[2048 + col] = a1; o[4096 + col] = a2; o[6144 + col] = a3;
}

// ------- fused: cache copy-out + append (inline 8-way partial reduce),
//         build RoPE'd K (bf16) + V (bf16). float4 path: j-pair per thread.
__global__ void k_prep_kv(const float* __restrict__ cache, const float* __restrict__ gpart,
                          const float* __restrict__ cost, const float* __restrict__ sint,
                          float* __restrict__ cache_out,
                          unsigned short* __restrict__ Kr, unsigned short* __restrict__ Vb) {
  int t = blockIdx.x * 256 + threadIdx.x;   // 4*2048*16*32 = 2^22 threads
  int j2 = t & 31, h = (t >> 5) & 15, pos = (t >> 9) & 2047, b = t >> 20;
  int f = h * DH + j2 * 2;                  // even
  float4 x, y;                              // {k(f),v(f),k(f+1),v(f+1)}, same at f+64
  if (pos < LC) {
    const float* p = cache + ((size_t)(b * LC + pos) * F_ + f) * 2;
    x = *(const float4*)p;
    y = *(const float4*)(p + 128);          // f + 64
  } else {
    float k0 = 0, v0 = 0, k1 = 0, v1 = 0, k2 = 0, v2 = 0, k3 = 0, v3 = 0;
#pragma unroll
    for (int z = 0; z < 8; ++z) {
      const float* gk = gpart + (size_t)z * 8192 + b * 2048;
      const float* gv = gpart + (size_t)(8 + z) * 8192 + b * 2048;
      k0 += gk[f];      k1 += gk[f + 1];
      k2 += gk[f + 64]; k3 += gk[f + 65];
      v0 += gv[f];      v1 += gv[f + 1];
      v2 += gv[f + 64]; v3 += gv[f + 65];
    }
    x = make_float4(k0, v0, k1, v1);
    y = make_float4(k2, v2, k3, v3);
  }
  float* o = cache_out + ((size_t)(b * LK + pos) * F_ + f) * 2;
  *(float4*)o = x;
  *(float4*)(o + 128) = y;
  int j = j2 * 2;
  float c0 = cost[pos * 64 + j],     s0 = sint[pos * 64 + j];
  float c1 = cost[pos * 64 + j + 1], s1 = sint[pos * 64 + j + 1];
  size_t kb = ((size_t)(b * H_ + h) * LK + pos) * DH + j;
  *(unsigned*)&Kr[kb]      = pack_bf2_rne(x.x * c0 - y.x * s0, x.z * c1 - y.z * s1);
  *(unsigned*)&Kr[kb + 64] = pack_bf2_rne(y.x * c0 + x.x * s0, y.z * c1 + x.z * s1);
  *(unsigned*)&Vb[kb]      = pack_bf2_rne(x.y, x.w);
  *(unsigned*)&Vb[kb + 64] = pack_bf2_rne(y.y, y.w);
}

// ------- z<2: W [K][N] f32 -> Wt [N][K] bf16;  z>=2: q f32 -> bf16 ------
__global__ void k_transpose_w(const float* __restrict__ Wq, const float* __restrict__ Wo,
                              unsigned short* __restrict__ WqT, unsigned short* __restrict__ WoT,
                              const float* __restrict__ qf, unsigned short* __restrict__ qb) {
  __shared__ float tile[32][33];
  int z = blockIdx.z;
  if (z >= 2) {
    int t = ((z - 2) * 4096 + blockIdx.y * 64 + blockIdx.x) * 256 + threadIdx.x;
    float4 v = ((const float4*)qf)[t];
    ushort4 o;
    o.x = f2bf(v.x); o.y = f2bf(v.y); o.z = f2bf(v.z); o.w = f2bf(v.w);
    ((ushort4*)qb)[t] = o;
    return;
  }
  const float* W = z ? Wo : Wq;
  unsigned short* Wt = z ? WoT : WqT;
  int n0 = blockIdx.x * 32, k0 = blockIdx.y * 32;
  int tx = threadIdx.x & 31, ty = threadIdx.x >> 5;
#pragma unroll
  for (int p = 0; p < 4; ++p)
    tile[ty + p * 8][tx] = W[(size_t)(k0 + ty + p * 8) * F_ + n0 + tx];
  __syncthreads();
#pragma unroll
  for (int p = 0; p < 4; ++p)
    Wt[(size_t)(n0 + ty + p * 8) * F_ + k0 + tx] = f2bf(tile[tx][ty + p * 8]);
}

// ---- bf16 MFMA GEMM, 6-phase schedule (R14, verified) + XCD swizzle ----
// BM=256, BN=128, BK=64, 8 waves (512 thr), grid 256 blocks = 1/CU.
// T1: swz = (lin&7)*32 + (lin>>3): each XCD gets 32 contiguous tiles
// (2 A-panels = 2MB, L2-resident).
template <int MODE>
__launch_bounds__(512)
__global__ void k_gemm(const unsigned short* __restrict__ A, const unsigned short* __restrict__ Bt,
                       void* __restrict__ Cv, const float* __restrict__ cost,
                       const float* __restrict__ sint, int M, int N, int K) {
  __shared__ __align__(16) unsigned short SM[49152];  // A:2x16384, B:2x8192 (ushorts)
  int tid = threadIdx.x, wid = tid >> 6, l = tid & 63;
  int wm = wid >> 1, wn = wid & 1;
  int lr = l & 15, lg = l >> 4;
  int lin = blockIdx.y * gridDim.x + blockIdx.x;
  int nwg = gridDim.x * gridDim.y;
  int swz = (lin & 7) * (nwg >> 3) + (lin >> 3);
  int m0 = (swz / gridDim.x) * 256, n0 = (swz % gridDim.x) * 128;

  int agoff[4], aloff[4], bgoff[2], bloff[2];
#pragma unroll
  for (int p = 0; p < 4; ++p) {
    int g = (p >> 1) * 1024 + (p & 1) * 512 + tid;
    int row = g >> 3, c = g & 7;
    agoff[p] = row * K + (c ^ (row & 7)) * 8;
    aloff[p] = g * 8;
  }
#pragma unroll
  for (int p = 0; p < 2; ++p) {
    int g = p * 512 + tid;
    int row = g >> 3, c = g & 7;
    bgoff[p] = row * K + (c ^ (row & 7)) * 8;
    bloff[p] = g * 8;
  }
  const unsigned short* Ag = A + (size_t)m0 * K;
  const unsigned short* Bg = Bt + (size_t)n0 * K;

  int fsw = (lr & 7);
  f32x4 acc[4][4];
#pragma unroll
  for (int i = 0; i < 4; ++i)
#pragma unroll
    for (int j = 0; j < 4; ++j) acc[i][j] = (f32x4){0.f, 0.f, 0.f, 0.f};

  int nk = K >> 6;
  // prologue: stage tile 0 into buf0
#pragma unroll
  for (int p = 0; p < 4; ++p) GLD16(Ag + agoff[p], SM + aloff[p]);
#pragma unroll
  for (int p = 0; p < 2; ++p) GLD16(Bg + bgoff[p], SM + 32768 + bloff[p]);

  for (int kt = 0; kt < nk; ++kt) {
    int cur = kt & 1;
    unsigned short* Ac = SM + cur * 16384;
    unsigned short* Bc = SM + 32768 + cur * 8192;
    unsigned short* An = SM + (cur ^ 1) * 16384;
    unsigned short* Bn = SM + 32768 + (cur ^ 1) * 8192;
    int knext = ((kt + 1 < nk) ? (kt + 1) : 0) << 6;

    __builtin_amdgcn_s_barrier();          // all waves done reading buf^1
    __builtin_amdgcn_sched_barrier(0);
    // stage A-half0 of t+1
    GLD16(Ag + knext + agoff[0], An + aloff[0]);
    GLD16(Ag + knext + agoff[1], An + aloff[1]);
    asm volatile("s_waitcnt vmcnt(2)" ::: "memory");   // tile t's 6 loads done
    __builtin_amdgcn_sched_barrier(0);
    __builtin_amdgcn_s_barrier();          // tile t visible to all waves
    __builtin_amdgcn_sched_barrier(0);

    // ---- P0: read all A-frags + B ni=0; stage A-half1; MFMA ni=0 ----
    bf16x8 af[2][4], bf0[2];
#pragma unroll
    for (int kw = 0; kw < 2; ++kw)
#pragma unroll
      for (int mi = 0; mi < 4; ++mi)
        af[kw][mi] = *(const bf16x8*)&Ac[(wm * 64 + mi * 16 + lr) * 64 + (((kw * 4 + lg) ^ fsw) << 3)];
#pragma unroll
    for (int kw = 0; kw < 2; ++kw)
      bf0[kw] = *(const bf16x8*)&Bc[(wn * 64 + lr) * 64 + (((kw * 4 + lg) ^ fsw) << 3)];
    GLD16(Ag + knext + agoff[2], An + aloff[2]);
    GLD16(Ag + knext + agoff[3], An + aloff[3]);
    asm volatile("s_waitcnt lgkmcnt(0)" ::: "memory");
    __builtin_amdgcn_sched_barrier(0);
    __builtin_amdgcn_s_setprio(1);
#pragma unroll
    for (int kw = 0; kw < 2; ++kw)
#pragma unroll
      for (int mi = 0; mi < 4; ++mi)
        acc[mi][0] = __builtin_amdgcn_mfma_f32_16x16x32_bf16(af[kw][mi], bf0[kw], acc[mi][0], 0, 0, 0);
    __builtin_amdgcn_s_setprio(0);
    __builtin_amdgcn_s_barrier();

    // ---- P1: B ni=1; stage B of t+1; MFMA ni=1 ----
#pragma unroll
    for (int kw = 0; kw < 2; ++kw)
      bf0[kw] = *(const bf16x8*)&Bc[(wn * 64 + 16 + lr) * 64 + (((kw * 4 + lg) ^ fsw) << 3)];
    GLD16(Bg + knext + bgoff[0], Bn + bloff[0]);
    GLD16(Bg + knext + bgoff[1], Bn + bloff[1]);
    asm volatile("s_waitcnt lgkmcnt(0)" ::: "memory");
    __builtin_amdgcn_sched_barrier(0);
    __builtin_amdgcn_s_setprio(1);
#pragma unroll
    for (int kw = 0; kw < 2; ++kw)
#pragma unroll
      for (int mi = 0; mi < 4; ++mi)
        acc[mi][1] = __builtin_amdgcn_mfma_f32_16x16x32_bf16(af[kw][mi], bf0[kw], acc[mi][1], 0, 0, 0);
    __builtin_amdgcn_s_setprio(0);
    __builtin_amdgcn_s_barrier();

    // ---- P2: B ni=2; MFMA ni=2 ----
#pragma unroll
    for (int kw = 0; kw < 2; ++kw)
      bf0[kw] = *(const bf16x8*)&Bc[(wn * 64 + 32 + lr) * 64 + (((kw * 4 + lg) ^ fsw) << 3)];
    asm volatile("s_waitcnt lgkmcnt(0)" ::: "memory");
    __builtin_amdgcn_sched_barrier(0);
    __builtin_amdgcn_s_setprio(1);
#pragma unroll
    for (int kw = 0; kw < 2; ++kw)
#pragma unroll
      for (int mi = 0; mi < 4; ++mi)
        acc[mi][2] = __builtin_amdgcn_mfma_f32_16x16x32_bf16(af[kw][mi], bf0[kw], acc[mi][2], 0, 0, 0);
    __builtin_amdgcn_s_setprio(0);
    __builtin_amdgcn_s_barrier();

    // ---- P3: B ni=3; MFMA ni=3 ----
#pragma unroll
    for (int kw = 0; kw < 2; ++kw)
      bf0[kw] = *(const bf16x8*)&Bc[(wn * 64 + 48 + lr) * 64 + (((kw * 4 + lg) ^ fsw) << 3)];
    asm volatile("s_waitcnt lgkmcnt(0)" ::: "memory");
    __builtin_amdgcn_sched_barrier(0);
    __builtin_amdgcn_s_setprio(1);
#pragma unroll
    for (int kw = 0; kw < 2; ++kw)
#pragma unroll
      for (int mi = 0; mi < 4; ++mi)
        acc[mi][3] = __builtin_amdgcn_mfma_f32_16x16x32_bf16(af[kw][mi], bf0[kw], acc[mi][3], 0, 0, 0);
    __builtin_amdgcn_s_setprio(0);
  }
  // drain the dummy prefetch before LDS reuse / exit
  asm volatile("s_waitcnt vmcnt(0)" ::: "memory");
  __syncthreads();

  if (MODE == 0) {
#pragma unroll
    for (int mi = 0; mi < 4; ++mi)
#pragma unroll
      for (int ni = 0; ni < 4; ++ni) {
        int row = m0 + wm * 64 + mi * 16 + lg * 4;
        int col = n0 + wn * 64 + ni * 16 + lr;
#pragma unroll
        for (int r = 0; r < 4; ++r)
          ((float*)Cv)[(size_t)(row + r) * N + col] = acc[mi][ni][r];
      }
  } else {
    // ---- fused RoPE epilogue (BN = 128 = head dim) ----
    unsigned short* X = SM;                 // [256][130] bf16 exchange tile
#pragma unroll
    for (int mi = 0; mi < 4; ++mi)
#pragma unroll
      for (int ni = 0; ni < 4; ++ni) {
        int lrow = wm * 64 + mi * 16 + lg * 4;
        int col = wn * 64 + ni * 16 + lr;
#pragma unroll
        for (int r = 0; r < 4; ++r)
          X[(lrow + r) * 130 + col] = f2bf(acc[mi][ni][r]);
      }
    __syncthreads();
    int h = swz % gridDim.x;
    const float scale = 0.12751743343788055f;  // (1/sqrt(128)) * log2(e)
    unsigned short* Q = (unsigned short*)Cv;
#pragma unroll
    for (int mi = 0; mi < 4; ++mi) {
      int lrow0 = wm * 64 + mi * 16 + lg * 4;
#pragma unroll
      for (int r = 0; r < 4; ++r) {
        int lrow = lrow0 + r;
        int grow = m0 + lrow;
        int qi = grow & 1023, b = grow >> 10;
        size_t obase = ((size_t)(b * H_ + h) * LQ + qi) * DH;
#pragma unroll
        for (int ni = 0; ni < 4; ++ni) {
          int col = wn * 64 + ni * 16 + lr;
          int jj = col & 63;
          float c = cost[qi * 64 + jj], s = sint[qi * 64 + jj];
          float a = acc[mi][ni][r];
          float a2 = bf2f(X[lrow * 130 + (col ^ 64)]);
          float o = (col < 64) ? (a * c - a2 * s) : (a * c + a2 * s);
          Q[obase + col] = f2bf(o * scale);
        }
      }
    }
  }
}

// --- flash attention: 4 waves x 32 q-rows, BK=64, single-buffer K -------
// (R16 kernel: 107.6 us, VGPR 116, no spill.)
__launch_bounds__(256, 2)
__global__ void k_attn(const unsigned short* __restrict__ Qr, const unsigned short* __restrict__ Kr,
                       const unsigned short* __restrict__ Vb, unsigned short* __restrict__ Oo) {
  __shared__ __align__(16) unsigned short Ks[64 * 128];     // 16 KB, chunk-swizzled
  __shared__ __align__(16) unsigned short Vt[128][72];      // 18 KB
  __shared__ __align__(16) unsigned short Pb[4][32][72];    // 18 KB
  int tid = threadIdx.x, wid = tid >> 6, l = tid & 63;
  int lr = l & 15, lg = l >> 4;
  int bh = blockIdx.x, q0 = blockIdx.y * 128 + wid * 32;    // grid (64,8)
  const unsigned short* Qb = Qr + ((size_t)bh * LQ + q0) * DH;
  const unsigned short* Kb = Kr + (size_t)bh * LK * DH;
  const unsigned short* Vp = Vb + (size_t)bh * LK * DH;

  bf16x8 qf[2][4];
#pragma unroll
  for (int s = 0; s < 2; ++s)
#pragma unroll
    for (int c = 0; c < 4; ++c)
      qf[s][c] = *(const bf16x8*)(Qb + (size_t)(s * 16 + lr) * DH + c * 32 + lg * 8);

  u16x8 one_u;
#pragma unroll
  for (int e = 0; e < 8; ++e) one_u[e] = 0x3F80;
  bf16x8 vone = *(const bf16x8*)&one_u;

  int gkoff[4], lkoff[4];
#pragma unroll
  for (int p = 0; p < 4; ++p) {
    int g = tid + p * 256, row = g >> 4, cc = g & 15;
    gkoff[p] = row * DH + (cc ^ (row & 15)) * 8;
    lkoff[p] = g * 8;
  }

  f32x4 oacc[2][8];
#pragma unroll
  for (int s = 0; s < 2; ++s)
#pragma unroll
    for (int i = 0; i < 8; ++i) oacc[s][i] = (f32x4){0.f, 0.f, 0.f, 0.f};
  f32x4 lacc[2] = {(f32x4){0.f, 0.f, 0.f, 0.f}, (f32x4){0.f, 0.f, 0.f, 0.f}};
  float mrun[2][4] = {{-1e30f, -1e30f, -1e30f, -1e30f}, {-1e30f, -1e30f, -1e30f, -1e30f}};

  int kp = tid >> 4, cg = tid & 15;

  // prologue: V(0) -> regs (keys kp, kp+16, kp+32, kp+48)
  const unsigned short* vs0 = Vp + (size_t)kp * DH + cg * 8;
  u16x8 v00 = *(const u16x8*)(vs0);
  u16x8 v01 = *(const u16x8*)(vs0 + 16 * DH);
  u16x8 v10 = *(const u16x8*)(vs0 + 32 * DH);
  u16x8 v11 = *(const u16x8*)(vs0 + 48 * DH);

  for (int kt = 0; kt < NT; ++kt) {
    __builtin_amdgcn_s_barrier();      // A: all waves done reading tile t-1
    __builtin_amdgcn_sched_barrier(0);
    // stage K(t) async into the single K buffer
    {
      const unsigned short* Kt = Kb + (size_t)kt * 64 * DH;
#pragma unroll
      for (int p = 0; p < 4; ++p) GLD16(Kt + gkoff[p], Ks + lkoff[p]);
    }
    // V(t) ds_writes from regs (packed u32, swizzled)
#pragma unroll
    for (int pp = 0; pp < 2; ++pp) {
      int j = kp + pp * 16;
      int kks = j ^ ((cg & 7) << 2);
      u16x8 a = pp ? v10 : v00, b2 = pp ? v11 : v01;
#pragma unroll
      for (int e = 0; e < 8; ++e) {
        unsigned pack = (unsigned)a[e] | ((unsigned)b2[e] << 16);
        *(unsigned*)&Vt[cg * 8 + e][kks * 2] = pack;
      }
    }
    // prefetch V(t+1) into regs (dummy re-read of t on last iter)
    {
      int tn = (kt + 1 < NT) ? kt + 1 : kt;
      const unsigned short* vn = Vp + (size_t)(tn * 64 + kp) * DH + cg * 8;
      v00 = *(const u16x8*)(vn);
      v01 = *(const u16x8*)(vn + 16 * DH);
      v10 = *(const u16x8*)(vn + 32 * DH);
      v11 = *(const u16x8*)(vn + 48 * DH);
    }
    // K(t)'s 4 GLD16 (oldest) done; V(t+1) still flying; Vt writes committed
    asm volatile("s_waitcnt vmcnt(4) lgkmcnt(0)" ::: "memory");
    __builtin_amdgcn_sched_barrier(0);
    __builtin_amdgcn_s_barrier();      // B: K(t) + Vt(t) visible to all
    __builtin_amdgcn_sched_barrier(0);

    // S = Q K^T : K fragment loaded once, used by both subtiles
    f32x4 sf[2][4];
    __builtin_amdgcn_s_setprio(1);
#pragma unroll
    for (int ct = 0; ct < 4; ++ct) {
      f32x4 s0 = (f32x4){0.f, 0.f, 0.f, 0.f};
      f32x4 s1 = (f32x4){0.f, 0.f, 0.f, 0.f};
#pragma unroll
      for (int ck = 0; ck < 4; ++ck) {
        bf16x8 kf = *(const bf16x8*)&Ks[(ct * 16 + lr) * 128 + (((ck * 4 + lg) ^ lr) << 3)];
        s0 = __builtin_amdgcn_mfma_f32_16x16x32_bf16(qf[0][ck], kf, s0, 0, 0, 0);
        s1 = __builtin_amdgcn_mfma_f32_16x16x32_bf16(qf[1][ck], kf, s1, 0, 0, 0);
      }
      sf[0][ct] = s0; sf[1][ct] = s1;
    }
    __builtin_amdgcn_s_setprio(0);

    // defer-max online softmax (both subtiles share the skip test)
    float pmax[2][4];
    bool allok = true;
#pragma unroll
    for (int s = 0; s < 2; ++s)
#pragma unroll
      for (int r = 0; r < 4; ++r) {
        pmax[s][r] = fmaxf(fmaxf(sf[s][0][r], sf[s][1][r]), fmaxf(sf[s][2][r], sf[s][3][r]));
        allok = allok && (pmax[s][r] - mrun[s][r] <= 8.0f);
      }
    if (!__all(allok)) {
#pragma unroll
      for (int s = 0; s < 2; ++s)
#pragma unroll
        for (int r = 0; r < 4; ++r) {
          float m = pmax[s][r];
#pragma unroll
          for (int off = 1; off < 16; off <<= 1) m = fmaxf(m, __shfl_xor(m, off));
          float mnew = fmaxf(mrun[s][r], m);
          float scl = exp2f(mrun[s][r] - mnew);
          lacc[s][r] *= scl;
#pragma unroll
          for (int dt = 0; dt < 8; ++dt) oacc[s][dt][r] *= scl;
          mrun[s][r] = mnew;
        }
    }
    // P stores: two packed u32 per (s,r) at permuted cols lr and 16+lr
#pragma unroll
    for (int s = 0; s < 2; ++s)
#pragma unroll
      for (int r = 0; r < 4; ++r) {
        float p0 = exp2f(sf[s][0][r] - mrun[s][r]);
        float p1 = exp2f(sf[s][1][r] - mrun[s][r]);
        float p2 = exp2f(sf[s][2][r] - mrun[s][r]);
        float p3 = exp2f(sf[s][3][r] - mrun[s][r]);
        unsigned* row = (unsigned*)&Pb[wid][s * 16 + lg * 4 + r][0];
        row[lr]      = pack_bf2(p0, p1);
        row[16 + lr] = pack_bf2(p2, p3);
      }

    // O += P V : V fragment loaded once, used by both subtiles
    bf16x8 pf00 = *(const bf16x8*)&Pb[wid][lr][lg * 8];
    bf16x8 pf01 = *(const bf16x8*)&Pb[wid][lr][32 + lg * 8];
    bf16x8 pf10 = *(const bf16x8*)&Pb[wid][16 + lr][lg * 8];
    bf16x8 pf11 = *(const bf16x8*)&Pb[wid][16 + lr][32 + lg * 8];
    __builtin_amdgcn_s_setprio(1);
    // l-rowsum via ones-MFMA (every lane ends with its row's full sum)
    lacc[0] = __builtin_amdgcn_mfma_f32_16x16x32_bf16(pf00, vone, lacc[0], 0, 0, 0);
    lacc[0] = __builtin_amdgcn_mfma_f32_16x16x32_bf16(pf01, vone, lacc[0], 0, 0, 0);
    lacc[1] = __builtin_amdgcn_mfma_f32_16x16x32_bf16(pf10, vone, lacc[1], 0, 0, 0);
    lacc[1] = __builtin_amdgcn_mfma_f32_16x16x32_bf16(pf11, vone, lacc[1], 0, 0, 0);
#pragma unroll
    for (int dt = 0; dt < 8; ++dt) {
      int d = dt * 16 + lr;
      int x = (d >> 3) & 7;
      bf16x8 v0 = *(const bf16x8*)&Vt[d][(lg ^ x) << 3];
      bf16x8 v1 = *(const bf16x8*)&Vt[d][((4 + lg) ^ x) << 3];
      oacc[0][dt] = __builtin_amdgcn_mfma_f32_16x16x32_bf16(pf00, v0, oacc[0][dt], 0, 0, 0);
      oacc[0][dt] = __builtin_amdgcn_mfma_f32_16x16x32_bf16(pf01, v1, oacc[0][dt], 0, 0, 0);
      oacc[1][dt] = __builtin_amdgcn_mfma_f32_16x16x32_bf16(pf10, v0, oacc[1][dt], 0, 0, 0);
      oacc[1][dt] = __builtin_amdgcn_mfma_f32_16x16x32_bf16(pf11, v1, oacc[1][dt], 0, 0, 0);
    }
    __builtin_amdgcn_s_setprio(0);
  }

  int b = bh >> 4, h = bh & 15;
#pragma unroll
  for (int s = 0; s < 2; ++s)
#pragma unroll
    for (int r = 0; r < 4; ++r) {
      float inv = 1.0f / lacc[s][r];
      int qrow = q0 + s * 16 + lg * 4 + r;
      size_t base = ((size_t)(b * LQ + qrow)) * F_ + h * DH;
#pragma unroll
      for (int dt = 0; dt < 8; ++dt)
        Oo[base + dt * 16 + lr] = f2bf(oacc[s][dt][r] * inv);
    }
}

extern "C" void kernel_launch(void* const* d_in, const int* in_sizes, int n_in,
                              void* d_out, int out_size, void* d_ws, size_t ws_size,
                              hipStream_t stream) {
  const float* kv    = (const float*)d_in[0];
  const float* q     = (const float*)d_in[1];
  const float* cache = (const float*)d_in[2];
  const float* Wq    = (const float*)d_in[3];
  const float* Wk    = (const float*)d_in[4];
  const float* Wv    = (const float*)d_in[5];
  const float* Wo    = (const float*)d_in[6];

  float* logits    = (float*)d_out;
  float* cache_out = logits + (size_t)B_ * LQ * F_;

  char* ws = (char*)d_ws;
  float* cost          = (float*)(ws);                       // 512 KB
  float* sint          = (float*)(ws + 524288);              // 512 KB
  float* gpart         = (float*)(ws + 1114112);             // 512 KB
  unsigned short* WqT  = (unsigned short*)(ws + 1638400);    // 8 MB
  unsigned short* WoT  = (unsigned short*)(ws + 10027008);   // 8 MB
  unsigned short* qbf  = (unsigned short*)(ws + 18415616);   // 16 MB
  unsigned short* Qro  = (unsigned short*)(ws + 35192832);   // 16 MB
  unsigned short* Kro  = (unsigned short*)(ws + 51970048);   // 32 MB
  unsigned short* Vbf  = (unsigned short*)(ws + 85524480);   // 32 MB
  unsigned short* attno = (unsigned short*)(ws + 127467520); // 16 MB

  k_tables<<<dim3(512), dim3(256), 0, stream>>>(cost, sint);
  k_gemv_part<<<dim3(8, 2, 8), dim3(256), 0, stream>>>(kv, Wk, Wv, gpart);
  k_prep_kv<<<dim3(16384), dim3(256), 0, stream>>>(cache, gpart, cost, sint,
                                                   cache_out, Kro, Vbf);
  k_transpose_w<<<dim3(64, 64, 4), dim3(256), 0, stream>>>(Wq, Wo, WqT, WoT, q, qbf);
  k_gemm<2><<<dim3(16, 16), dim3(512), 0, stream>>>(qbf, WqT, Qro, cost, sint,
                                                    B_ * LQ, F_, F_);
  k_attn<<<dim3(64, 8), dim3(256), 0, stream>>>(Qro, Kro, Vbf, attno);
  k_gemm<0><<<dim3(16, 16), dim3(512), 0, stream>>>(attno, WoT, logits, nullptr, nullptr,
                                                    B_ * LQ, F_, F_);
}